// Round 1
// baseline (256.900 us; speedup 1.0000x reference)
//
#include <hip/hip_runtime.h>

// GCN block: delta = segment_sum( (x @ W^T)[source] * ew, target )
//          = segment_sum( x[source] * ew, target ) @ W^T   (linearity)
// Phase 1: s[tgt] += ew * x[src]   (atomic scatter, s in d_ws)
// Phase 2: out = s @ W^T           (dense 100K x 64 x 64 GEMM)

#define D 64   // D_IN == D_OUT == 64

// ---------------- Phase 1: edge scatter ----------------
// One wave (64 lanes) per edge; lane = feature column.
// src/tgt/ew indices are wave-uniform -> scalar loads.
__global__ __launch_bounds__(256) void gcn_scatter_kernel(
    const float* __restrict__ x, const float* __restrict__ ew,
    const int* __restrict__ src, const int* __restrict__ tgt,
    float* __restrict__ s, int n_edges)
{
    int lane = threadIdx.x & 63;
    int e = blockIdx.x * 4 + (threadIdx.x >> 6);
    if (e >= n_edges) return;
    int sn = src[e];
    int tn = tgt[e];
    float w = ew[e];
    float v = x[(size_t)sn * D + lane] * w;   // coalesced 256B per wave, L3-cached
    atomicAdd(&s[(size_t)tn * D + lane], v);  // global_atomic_add_f32
}

// ---------------- Phase 2: out = s @ W^T ----------------
// Block = 256 threads = 4 waves. Block tile: 64 rows x 64 cols.
// lane = row within tile; wave id selects 16 output cols (wave-uniform ->
// W loads become s_load, served by scalar cache; W is 16KB, fully cached).
// s tile staged in LDS (padded), read as float4.
__global__ __launch_bounds__(256) void gcn_gemm_kernel(
    const float* __restrict__ s, const float* __restrict__ W,
    float* __restrict__ out, int n_nodes)
{
    __shared__ float4 xs[64 * 17];   // 64 rows x 68 floats (pad 4) = 17 float4/row

    const int tid  = threadIdx.x;
    const int lane = tid & 63;
    const int wid  = __builtin_amdgcn_readfirstlane(tid >> 6);
    const int row0 = blockIdx.x * 64;

    // Stage 64x64 f32 tile: 1024 float4, 4 per thread, coalesced.
    const float4* s4 = reinterpret_cast<const float4*>(s);
#pragma unroll
    for (int k = 0; k < 4; ++k) {
        int f  = tid + k * 256;      // float4 index 0..1023
        int r  = f >> 4;             // row 0..63
        int c4 = f & 15;             // float4 col 0..15
        float4 v = make_float4(0.f, 0.f, 0.f, 0.f);
        if (row0 + r < n_nodes)
            v = s4[(size_t)(row0 + r) * 16 + c4];
        xs[r * 17 + c4] = v;
    }
    __syncthreads();

    float acc[16];
#pragma unroll
    for (int j = 0; j < 16; ++j) acc[j] = 0.f;

    const int o0 = wid * 16;         // wave-uniform output-column base
    const float4* W4 = reinterpret_cast<const float4*>(W);

#pragma unroll
    for (int d4 = 0; d4 < 16; ++d4) {
        float4 xv = xs[lane * 17 + d4];
#pragma unroll
        for (int j = 0; j < 16; ++j) {
            float4 wv = W4[(size_t)(o0 + j) * 16 + d4];   // wave-uniform -> s_load
            acc[j] += xv.x * wv.x + xv.y * wv.y + xv.z * wv.z + xv.w * wv.w;
        }
    }

    const int row = row0 + lane;
    if (row < n_nodes) {
        float4* out4 = reinterpret_cast<float4*>(out);
#pragma unroll
        for (int j4 = 0; j4 < 4; ++j4) {
            float4 v = make_float4(acc[j4 * 4 + 0], acc[j4 * 4 + 1],
                                   acc[j4 * 4 + 2], acc[j4 * 4 + 3]);
            out4[(size_t)row * 16 + wid * 4 + j4] = v;
        }
    }
}

extern "C" void kernel_launch(void* const* d_in, const int* in_sizes, int n_in,
                              void* d_out, int out_size, void* d_ws, size_t ws_size,
                              hipStream_t stream)
{
    const float* x   = (const float*)d_in[0];
    const float* W   = (const float*)d_in[1];
    const float* ew  = (const float*)d_in[2];
    const int*   src = (const int*)d_in[3];
    const int*   tgt = (const int*)d_in[4];

    const int n_nodes = in_sizes[0] / D;
    const int n_edges = in_sizes[2];

    float* s = (float*)d_ws;
    const size_t s_bytes = (size_t)n_nodes * D * sizeof(float);

    // Zero the accumulator every call (harness does not re-poison between replays).
    hipMemsetAsync(d_ws, 0, s_bytes, stream);

    const int sblocks = (n_edges + 3) / 4;          // 4 edges (waves) per block
    gcn_scatter_kernel<<<sblocks, 256, 0, stream>>>(x, ew, src, tgt, s, n_edges);

    const int gblocks = (n_nodes + 63) / 64;        // 64 rows per block
    gcn_gemm_kernel<<<gblocks, 256, 0, stream>>>(s, W, (float*)d_out, n_nodes);
}

// Round 2
// 244.661 us; speedup vs baseline: 1.0500x; 1.0500x over previous
//
#include <hip/hip_runtime.h>

// GCN block: delta = segment_sum( (x @ W^T)[source] * ew, target )
//          = segment_sum( x[source] * ew, target ) @ W^T   (linearity)
//
// R2: replace 64M f32 atomics (write-through to HBM, 256 MB WRITE_SIZE,
// atomic-throughput bound at ~220us) with counting-sort by target +
// atomic-free segmented reduction:
//   1. hist[t] = degree          (1M int atomics, L2-resident)
//   2. starts = exclusive_scan(hist)
//   3. scatter (src, ew) into target-sorted order (1M slot atomics)
//   4. segreduce: one wave per target, s[t] = sum(ew * x[src]) — no atomics,
//      writes every row (zero-fill included, no memset of s needed)
//   5. out = s @ W^T

#define D 64   // D_IN == D_OUT == 64

// ---------------- fallback: atomic edge scatter (R1 kernel) ----------------
__global__ __launch_bounds__(256) void gcn_scatter_kernel(
    const float* __restrict__ x, const float* __restrict__ ew,
    const int* __restrict__ src, const int* __restrict__ tgt,
    float* __restrict__ s, int n_edges)
{
    int lane = threadIdx.x & 63;
    int e = blockIdx.x * 4 + (threadIdx.x >> 6);
    if (e >= n_edges) return;
    int sn = src[e];
    int tn = tgt[e];
    float w = ew[e];
    float v = x[(size_t)sn * D + lane] * w;
    atomicAdd(&s[(size_t)tn * D + lane], v);
}

// ---------------- 1. histogram of targets ----------------
__global__ __launch_bounds__(256) void hist_kernel(
    const int* __restrict__ tgt, int* __restrict__ hist, int n_edges)
{
    int i = blockIdx.x * 256 + threadIdx.x;
    if (i < n_edges) atomicAdd(&hist[tgt[i]], 1);
}

// ---------------- 2a. per-chunk sums (chunk = 1024 elements) ----------------
__global__ __launch_bounds__(256) void chunk_sum_kernel(
    const int* __restrict__ hist, int* __restrict__ blkSums, int n)
{
    __shared__ int lds[256];
    const int tid = threadIdx.x;
    const int base = blockIdx.x * 1024 + tid * 4;
    int4 v = make_int4(0, 0, 0, 0);
    if (base + 3 < n) v = *reinterpret_cast<const int4*>(hist + base);
    else {
        if (base + 0 < n) v.x = hist[base + 0];
        if (base + 1 < n) v.y = hist[base + 1];
        if (base + 2 < n) v.z = hist[base + 2];
    }
    lds[tid] = v.x + v.y + v.z + v.w;
    __syncthreads();
    for (int off = 128; off > 0; off >>= 1) {
        if (tid < off) lds[tid] += lds[tid + off];
        __syncthreads();
    }
    if (tid == 0) blkSums[blockIdx.x] = lds[0];
}

// ---------------- 2b. exclusive scan of chunk sums (nb <= 1024) ------------
__global__ __launch_bounds__(1024) void scan_blk_kernel(
    int* __restrict__ blkSums, int nb)
{
    __shared__ int lds[1024];
    const int tid = threadIdx.x;
    int v = (tid < nb) ? blkSums[tid] : 0;
    lds[tid] = v;
    __syncthreads();
    for (int off = 1; off < 1024; off <<= 1) {
        int a = (tid >= off) ? lds[tid - off] : 0;
        __syncthreads();
        lds[tid] += a;
        __syncthreads();
    }
    if (tid < nb) blkSums[tid] = lds[tid] - v;   // exclusive
}

// ---------------- 2c. per-chunk exclusive scan + apply offsets -------------
__global__ __launch_bounds__(256) void scan_apply_kernel(
    const int* __restrict__ hist, const int* __restrict__ blkSums,
    int* __restrict__ starts, int* __restrict__ cursor, int n)
{
    __shared__ int lds[256];
    const int tid = threadIdx.x;
    const int base = blockIdx.x * 1024 + tid * 4;
    int4 v = make_int4(0, 0, 0, 0);
    if (base + 3 < n) v = *reinterpret_cast<const int4*>(hist + base);
    else {
        if (base + 0 < n) v.x = hist[base + 0];
        if (base + 1 < n) v.y = hist[base + 1];
        if (base + 2 < n) v.z = hist[base + 2];
    }
    const int tsum = v.x + v.y + v.z + v.w;
    lds[tid] = tsum;
    __syncthreads();
    for (int off = 1; off < 256; off <<= 1) {
        int a = (tid >= off) ? lds[tid - off] : 0;
        __syncthreads();
        lds[tid] += a;
        __syncthreads();
    }
    int pre = blkSums[blockIdx.x] + lds[tid] - tsum;   // exclusive prefix
    if (base + 0 < n) { starts[base + 0] = pre; cursor[base + 0] = pre; pre += v.x; }
    if (base + 1 < n) { starts[base + 1] = pre; cursor[base + 1] = pre; pre += v.y; }
    if (base + 2 < n) { starts[base + 2] = pre; cursor[base + 2] = pre; pre += v.z; }
    if (base + 3 < n) { starts[base + 3] = pre; cursor[base + 3] = pre; }
}

// ---------------- 3. scatter (src, ew) into target-sorted order ------------
__global__ __launch_bounds__(256) void scatter_ids_kernel(
    const int* __restrict__ src, const int* __restrict__ tgt,
    const float* __restrict__ ew, int* __restrict__ cursor,
    int* __restrict__ sortedSrc, float* __restrict__ sortedEw, int n_edges)
{
    int i = blockIdx.x * 256 + threadIdx.x;
    if (i >= n_edges) return;
    int t = tgt[i];
    int pos = atomicAdd(&cursor[t], 1);
    sortedSrc[pos] = src[i];
    sortedEw[pos]  = ew[i];
}

// ---------------- 4. segmented reduce: one wave per target ----------------
__global__ __launch_bounds__(256) void segreduce_kernel(
    const float* __restrict__ x, const int* __restrict__ starts,
    const int* __restrict__ sortedSrc, const float* __restrict__ sortedEw,
    float* __restrict__ s, int n_nodes, int n_edges)
{
    const int lane = threadIdx.x & 63;
    const int t = blockIdx.x * 4 + (threadIdx.x >> 6);
    if (t >= n_nodes) return;
    const int beg = starts[t];
    const int end = (t + 1 < n_nodes) ? starts[t + 1] : n_edges;
    float acc = 0.f;
    for (int e = beg; e < end; ++e) {
        int   sn = sortedSrc[e];     // wave-uniform (broadcast)
        float w  = sortedEw[e];
        acc += w * x[(size_t)sn * D + lane];   // coalesced 256B, L3-served
    }
    s[(size_t)t * D + lane] = acc;   // plain coalesced write, covers all rows
}

// ---------------- 5. out = s @ W^T ----------------
__global__ __launch_bounds__(256) void gcn_gemm_kernel(
    const float* __restrict__ s, const float* __restrict__ W,
    float* __restrict__ out, int n_nodes)
{
    __shared__ float4 xs[64 * 17];   // 64 rows x 68 floats (pad 4)

    const int tid  = threadIdx.x;
    const int lane = tid & 63;
    const int wid  = __builtin_amdgcn_readfirstlane(tid >> 6);
    const int row0 = blockIdx.x * 64;

    const float4* s4 = reinterpret_cast<const float4*>(s);
#pragma unroll
    for (int k = 0; k < 4; ++k) {
        int f  = tid + k * 256;
        int r  = f >> 4;
        int c4 = f & 15;
        float4 v = make_float4(0.f, 0.f, 0.f, 0.f);
        if (row0 + r < n_nodes)
            v = s4[(size_t)(row0 + r) * 16 + c4];
        xs[r * 17 + c4] = v;
    }
    __syncthreads();

    float acc[16];
#pragma unroll
    for (int j = 0; j < 16; ++j) acc[j] = 0.f;

    const int o0 = wid * 16;
    const float4* W4 = reinterpret_cast<const float4*>(W);

#pragma unroll
    for (int d4 = 0; d4 < 16; ++d4) {
        float4 xv = xs[lane * 17 + d4];
#pragma unroll
        for (int j = 0; j < 16; ++j) {
            float4 wv = W4[(size_t)(o0 + j) * 16 + d4];   // wave-uniform -> s_load
            acc[j] += xv.x * wv.x + xv.y * wv.y + xv.z * wv.z + xv.w * wv.w;
        }
    }

    const int row = row0 + lane;
    if (row < n_nodes) {
        float4* out4 = reinterpret_cast<float4*>(out);
#pragma unroll
        for (int j4 = 0; j4 < 4; ++j4) {
            float4 v = make_float4(acc[j4 * 4 + 0], acc[j4 * 4 + 1],
                                   acc[j4 * 4 + 2], acc[j4 * 4 + 3]);
            out4[(size_t)row * 16 + wid * 4 + j4] = v;
        }
    }
}

extern "C" void kernel_launch(void* const* d_in, const int* in_sizes, int n_in,
                              void* d_out, int out_size, void* d_ws, size_t ws_size,
                              hipStream_t stream)
{
    const float* x   = (const float*)d_in[0];
    const float* W   = (const float*)d_in[1];
    const float* ew  = (const float*)d_in[2];
    const int*   src = (const int*)d_in[3];
    const int*   tgt = (const int*)d_in[4];

    const int n_nodes = in_sizes[0] / D;
    const int n_edges = in_sizes[2];

    // ---- workspace layout (all 4B-aligned) ----
    float* s        = (float*)d_ws;                       // n_nodes * D
    int*   hist     = (int*)(s + (size_t)n_nodes * D);    // n_nodes
    int*   starts   = hist + n_nodes;                     // n_nodes
    int*   cursor   = starts + n_nodes;                   // n_nodes
    int*   blkSums  = cursor + n_nodes;                   // up to 1024
    int*   sortedSrc= blkSums + 1024;                     // n_edges
    float* sortedEw = (float*)(sortedSrc + n_edges);      // n_edges

    const size_t need = ((size_t)n_nodes * D + 3 * (size_t)n_nodes + 1024 +
                         2 * (size_t)n_edges) * sizeof(float);

    const int eblocks = (n_edges + 255) / 256;
    const int gblocks = (n_nodes + 63) / 64;

    if (ws_size < need) {
        // fallback: R1 atomic path (needs only s)
        hipMemsetAsync(s, 0, (size_t)n_nodes * D * sizeof(float), stream);
        gcn_scatter_kernel<<<(n_edges + 3) / 4, 256, 0, stream>>>(x, ew, src, tgt, s, n_edges);
        gcn_gemm_kernel<<<gblocks, 256, 0, stream>>>(s, W, (float*)d_out, n_nodes);
        return;
    }

    const int nb = (n_nodes + 1023) / 1024;               // 98 for 100K nodes

    hipMemsetAsync(hist, 0, (size_t)n_nodes * sizeof(int), stream);
    hist_kernel<<<eblocks, 256, 0, stream>>>(tgt, hist, n_edges);
    chunk_sum_kernel<<<nb, 256, 0, stream>>>(hist, blkSums, n_nodes);
    scan_blk_kernel<<<1, 1024, 0, stream>>>(blkSums, nb);
    scan_apply_kernel<<<nb, 256, 0, stream>>>(hist, blkSums, starts, cursor, n_nodes);
    scatter_ids_kernel<<<eblocks, 256, 0, stream>>>(src, tgt, ew, cursor,
                                                    sortedSrc, sortedEw, n_edges);
    segreduce_kernel<<<(n_nodes + 3) / 4, 256, 0, stream>>>(x, starts, sortedSrc,
                                                            sortedEw, s, n_nodes, n_edges);
    gcn_gemm_kernel<<<gblocks, 256, 0, stream>>>(s, W, (float*)d_out, n_nodes);
}

// Round 3
// 199.593 us; speedup vs baseline: 1.2871x; 1.2258x over previous
//
#include <hip/hip_runtime.h>

// GCN block: delta = segment_sum( (x @ W^T)[source] * ew, target )
//          = segment_sum( x[source] * ew, target ) @ W^T   (linearity)
//
// R3: counting-sort by target (pairs packed int2), then ONE fused kernel:
//   segreduce (pipelined: coalesced id-block load + shfl broadcast + 4-deep
//   unrolled x-row gathers) + per-node 64x64 GEMM epilogue via LDS.
// Eliminates the s intermediate (51 MB) and the separate GEMM dispatch.

#define D 64   // D_IN == D_OUT == 64

// ---------------- fallback: atomic edge scatter (R1) ----------------
__global__ __launch_bounds__(256) void gcn_scatter_kernel(
    const float* __restrict__ x, const float* __restrict__ ew,
    const int* __restrict__ src, const int* __restrict__ tgt,
    float* __restrict__ s, int n_edges)
{
    int lane = threadIdx.x & 63;
    int e = blockIdx.x * 4 + (threadIdx.x >> 6);
    if (e >= n_edges) return;
    int sn = src[e];
    int tn = tgt[e];
    float w = ew[e];
    float v = x[(size_t)sn * D + lane] * w;
    atomicAdd(&s[(size_t)tn * D + lane], v);
}

// ---------------- fallback: out = s @ W^T (R1) ----------------
__global__ __launch_bounds__(256) void gcn_gemm_kernel(
    const float* __restrict__ s, const float* __restrict__ W,
    float* __restrict__ out, int n_nodes)
{
    __shared__ float4 xs[64 * 17];
    const int tid  = threadIdx.x;
    const int lane = tid & 63;
    const int wid  = __builtin_amdgcn_readfirstlane(tid >> 6);
    const int row0 = blockIdx.x * 64;

    const float4* s4 = reinterpret_cast<const float4*>(s);
#pragma unroll
    for (int k = 0; k < 4; ++k) {
        int f  = tid + k * 256;
        int r  = f >> 4;
        int c4 = f & 15;
        float4 v = make_float4(0.f, 0.f, 0.f, 0.f);
        if (row0 + r < n_nodes)
            v = s4[(size_t)(row0 + r) * 16 + c4];
        xs[r * 17 + c4] = v;
    }
    __syncthreads();

    float acc[16];
#pragma unroll
    for (int j = 0; j < 16; ++j) acc[j] = 0.f;

    const int o0 = wid * 16;
    const float4* W4 = reinterpret_cast<const float4*>(W);
#pragma unroll
    for (int d4 = 0; d4 < 16; ++d4) {
        float4 xv = xs[lane * 17 + d4];
#pragma unroll
        for (int j = 0; j < 16; ++j) {
            float4 wv = W4[(size_t)(o0 + j) * 16 + d4];
            acc[j] += xv.x * wv.x + xv.y * wv.y + xv.z * wv.z + xv.w * wv.w;
        }
    }

    const int row = row0 + lane;
    if (row < n_nodes) {
        float4* out4 = reinterpret_cast<float4*>(out);
#pragma unroll
        for (int j4 = 0; j4 < 4; ++j4) {
            float4 v = make_float4(acc[j4 * 4 + 0], acc[j4 * 4 + 1],
                                   acc[j4 * 4 + 2], acc[j4 * 4 + 3]);
            out4[(size_t)row * 16 + wid * 4 + j4] = v;
        }
    }
}

// ---------------- 1. histogram of targets ----------------
__global__ __launch_bounds__(256) void hist_kernel(
    const int* __restrict__ tgt, int* __restrict__ hist, int n_edges)
{
    int i = blockIdx.x * 256 + threadIdx.x;
    if (i < n_edges) atomicAdd(&hist[tgt[i]], 1);
}

// ---------------- 2a. per-chunk sums (chunk = 1024) ----------------
__global__ __launch_bounds__(256) void chunk_sum_kernel(
    const int* __restrict__ hist, int* __restrict__ blkSums, int n)
{
    __shared__ int lds[256];
    const int tid = threadIdx.x;
    const int base = blockIdx.x * 1024 + tid * 4;
    int4 v = make_int4(0, 0, 0, 0);
    if (base + 3 < n) v = *reinterpret_cast<const int4*>(hist + base);
    else {
        if (base + 0 < n) v.x = hist[base + 0];
        if (base + 1 < n) v.y = hist[base + 1];
        if (base + 2 < n) v.z = hist[base + 2];
    }
    lds[tid] = v.x + v.y + v.z + v.w;
    __syncthreads();
    for (int off = 128; off > 0; off >>= 1) {
        if (tid < off) lds[tid] += lds[tid + off];
        __syncthreads();
    }
    if (tid == 0) blkSums[blockIdx.x] = lds[0];
}

// ---------------- 2b. exclusive scan of chunk sums (nb <= 1024) ------------
__global__ __launch_bounds__(1024) void scan_blk_kernel(
    int* __restrict__ blkSums, int nb)
{
    __shared__ int lds[1024];
    const int tid = threadIdx.x;
    int v = (tid < nb) ? blkSums[tid] : 0;
    lds[tid] = v;
    __syncthreads();
    for (int off = 1; off < 1024; off <<= 1) {
        int a = (tid >= off) ? lds[tid - off] : 0;
        __syncthreads();
        lds[tid] += a;
        __syncthreads();
    }
    if (tid < nb) blkSums[tid] = lds[tid] - v;   // exclusive
}

// ---------------- 2c. per-chunk exclusive scan + apply offsets -------------
__global__ __launch_bounds__(256) void scan_apply_kernel(
    const int* __restrict__ hist, const int* __restrict__ blkSums,
    int* __restrict__ starts, int* __restrict__ cursor, int n)
{
    __shared__ int lds[256];
    const int tid = threadIdx.x;
    const int base = blockIdx.x * 1024 + tid * 4;
    int4 v = make_int4(0, 0, 0, 0);
    if (base + 3 < n) v = *reinterpret_cast<const int4*>(hist + base);
    else {
        if (base + 0 < n) v.x = hist[base + 0];
        if (base + 1 < n) v.y = hist[base + 1];
        if (base + 2 < n) v.z = hist[base + 2];
    }
    const int tsum = v.x + v.y + v.z + v.w;
    lds[tid] = tsum;
    __syncthreads();
    for (int off = 1; off < 256; off <<= 1) {
        int a = (tid >= off) ? lds[tid - off] : 0;
        __syncthreads();
        lds[tid] += a;
        __syncthreads();
    }
    int pre = blkSums[blockIdx.x] + lds[tid] - tsum;
    if (base + 0 < n) { starts[base + 0] = pre; cursor[base + 0] = pre; pre += v.x; }
    if (base + 1 < n) { starts[base + 1] = pre; cursor[base + 1] = pre; pre += v.y; }
    if (base + 2 < n) { starts[base + 2] = pre; cursor[base + 2] = pre; pre += v.z; }
    if (base + 3 < n) { starts[base + 3] = pre; cursor[base + 3] = pre; }
}

// ---------------- 3. scatter packed (src, ew) into target-sorted order -----
__global__ __launch_bounds__(256) void scatter_ids_kernel(
    const int* __restrict__ src, const int* __restrict__ tgt,
    const float* __restrict__ ew, int* __restrict__ cursor,
    int2* __restrict__ pairs, int n_edges)
{
    int i = blockIdx.x * 256 + threadIdx.x;
    if (i >= n_edges) return;
    int t = tgt[i];
    int pos = atomicAdd(&cursor[t], 1);
    pairs[pos] = make_int2(src[i], __float_as_int(ew[i]));   // one 8B write
}

// ---------------- 4. fused segreduce + 64x64 GEMM epilogue ----------------
// Grid-stride, one wave per node. Per node:
//   - load up to 64 (src,ew) pairs coalesced, shfl-broadcast ids,
//     4-deep-unrolled x-row gathers (independent loads -> pipelined)
//   - acc row (one float/lane) -> wave-private LDS -> dot with W (in LDS,
//     row-padded to 65 so bank = (o+d)%32, conflict-free) -> out row.
__global__ __launch_bounds__(256) void fused_segreduce_gemm_kernel(
    const float* __restrict__ x, const int* __restrict__ starts,
    const int2* __restrict__ pairs, const float* __restrict__ W,
    float* __restrict__ out, int n_nodes, int n_edges, int total_waves)
{
    __shared__ float Wl[64 * 65];     // W[o][d] at Wl[o*65+d]
    __shared__ float accRow[4][64];   // one row per wave

    const int tid = threadIdx.x;
    for (int i = tid; i < 64 * 64; i += 256) {
        int o = i >> 6, d = i & 63;
        Wl[o * 65 + d] = W[i];
    }
    __syncthreads();                  // only barrier; waves diverge after this

    const int lane = tid & 63;
    const int wv   = tid >> 6;
    const int gw   = blockIdx.x * 4 + wv;

    for (int t = gw; t < n_nodes; t += total_waves) {
        const int beg = starts[t];
        const int end = (t + 1 < n_nodes) ? starts[t + 1] : n_edges;
        float acc = 0.f;

        for (int base = beg; base < end; base += 64) {
            const int rem = end - base;
            const int cnt = rem < 64 ? rem : 64;
            int2 pr = make_int2(0, 0);
            if (lane < cnt) pr = pairs[base + lane];   // coalesced 512B

            int j = 0;
            for (; j + 4 <= cnt; j += 4) {
                int   s0 = __shfl(pr.x, j + 0); float w0 = __int_as_float(__shfl(pr.y, j + 0));
                int   s1 = __shfl(pr.x, j + 1); float w1 = __int_as_float(__shfl(pr.y, j + 1));
                int   s2 = __shfl(pr.x, j + 2); float w2 = __int_as_float(__shfl(pr.y, j + 2));
                int   s3 = __shfl(pr.x, j + 3); float w3 = __int_as_float(__shfl(pr.y, j + 3));
                float x0 = x[(size_t)s0 * D + lane];   // 4 independent gathers
                float x1 = x[(size_t)s1 * D + lane];
                float x2 = x[(size_t)s2 * D + lane];
                float x3 = x[(size_t)s3 * D + lane];
                acc += w0 * x0; acc += w1 * x1; acc += w2 * x2; acc += w3 * x3;
            }
            for (; j < cnt; ++j) {
                int   sj = __shfl(pr.x, j);
                float wj = __int_as_float(__shfl(pr.y, j));
                acc += wj * x[(size_t)sj * D + lane];
            }
        }

        // ---- epilogue: out[t][o] = sum_d acc[d] * W[o][d], o = lane ----
        accRow[wv][lane] = acc;
        asm volatile("s_waitcnt lgkmcnt(0)" ::: "memory");   // wave-internal LDS fence

        float o_acc = 0.f;
#pragma unroll
        for (int d = 0; d < 64; ++d)
            o_acc += accRow[wv][d] * Wl[lane * 65 + d];      // broadcast + conflict-free
        out[(size_t)t * D + lane] = o_acc;

        asm volatile("s_waitcnt lgkmcnt(0)" ::: "memory");   // reads done before next write
    }
}

extern "C" void kernel_launch(void* const* d_in, const int* in_sizes, int n_in,
                              void* d_out, int out_size, void* d_ws, size_t ws_size,
                              hipStream_t stream)
{
    const float* x   = (const float*)d_in[0];
    const float* W   = (const float*)d_in[1];
    const float* ew  = (const float*)d_in[2];
    const int*   src = (const int*)d_in[3];
    const int*   tgt = (const int*)d_in[4];

    const int n_nodes = in_sizes[0] / D;
    const int n_edges = in_sizes[2];

    // ---- workspace layout ----
    int* hist    = (int*)d_ws;                    // n_nodes
    int* starts  = hist + n_nodes;                // n_nodes
    int* cursor  = starts + n_nodes;              // n_nodes
    int* blkSums = cursor + n_nodes;              // 1024
    size_t off_i = ((size_t)3 * n_nodes + 1024 + 1) & ~(size_t)1;  // 8B-align
    int2* pairs  = (int2*)((int*)d_ws + off_i);   // n_edges int2

    const size_t need = (off_i + 2 * (size_t)n_edges) * sizeof(int);

    const int eblocks = (n_edges + 255) / 256;

    if (ws_size < need) {
        // fallback: R1 atomic path (needs n_nodes*D floats)
        float* s = (float*)d_ws;
        hipMemsetAsync(s, 0, (size_t)n_nodes * D * sizeof(float), stream);
        gcn_scatter_kernel<<<(n_edges + 3) / 4, 256, 0, stream>>>(x, ew, src, tgt, s, n_edges);
        gcn_gemm_kernel<<<(n_nodes + 63) / 64, 256, 0, stream>>>(s, W, (float*)d_out, n_nodes);
        return;
    }

    const int nb = (n_nodes + 1023) / 1024;

    hipMemsetAsync(hist, 0, (size_t)n_nodes * sizeof(int), stream);
    hist_kernel<<<eblocks, 256, 0, stream>>>(tgt, hist, n_edges);
    chunk_sum_kernel<<<nb, 256, 0, stream>>>(hist, blkSums, n_nodes);
    scan_blk_kernel<<<1, 1024, 0, stream>>>(blkSums, nb);
    scan_apply_kernel<<<nb, 256, 0, stream>>>(hist, blkSums, starts, cursor, n_nodes);
    scatter_ids_kernel<<<eblocks, 256, 0, stream>>>(src, tgt, ew, cursor, pairs, n_edges);

    const int fblocks = 2048;                      // 8192 waves (max resident)
    fused_segreduce_gemm_kernel<<<fblocks, 256, 0, stream>>>(
        x, starts, pairs, W, (float*)d_out, n_nodes, n_edges, fblocks * 4);
}